// Round 1
// baseline (26.894 us; speedup 1.0000x reference)
//
#include <hip/hip_runtime.h>
#include <math.h>

#define LOG2PI 1.8378770664093453f  /* log(2*pi) */

// ---------------------------------------------------------------------------
// Kernel 1: S[s] = sum_d normal_log_prob[s][d]   (n_samples=4096, dim=16)
// ---------------------------------------------------------------------------
__global__ __launch_bounds__(256) void nlp_rowsum_kernel(
    const float* __restrict__ nlp, float* __restrict__ S, int n_samples)
{
    int s = blockIdx.x * blockDim.x + threadIdx.x;
    if (s < n_samples) {
        const float4* row = reinterpret_cast<const float4*>(nlp + (size_t)s * 16);
        float acc = 0.0f;
#pragma unroll
        for (int i = 0; i < 4; ++i) {
            float4 v = row[i];
            acc += v.x + v.y + v.z + v.w;
        }
        S[s] = acc;
    }
}

// ---------------------------------------------------------------------------
// Kernel 2: per-batch argmax over 4096 codebook rows.
//   score[b,s] = sum_d( -0.5*z^2 ) - sum_d(log std) - 8*log2pi - S[s]
//   z = (prior[s,d]-mu[b,d]) * (1/std[b,d])
// One block per b (1024 blocks), 256 threads; each thread scans 16 rows.
// ---------------------------------------------------------------------------
__global__ __launch_bounds__(256) void pfr_argmax_kernel(
    const float* __restrict__ mu_q, const float* __restrict__ std_q,
    const float* __restrict__ prior, const float* __restrict__ S,
    float* __restrict__ out_samples, float* __restrict__ out_idx)
{
    const int b   = blockIdx.x;
    const int tid = threadIdx.x;

    __shared__ float s_inv[16];
    __shared__ float s_ls[16];
    if (tid < 16) {
        float sd = std_q[b * 16 + tid];
        s_inv[tid] = 1.0f / sd;
        s_ls[tid]  = logf(sd);
    }
    __syncthreads();

    float mu[16], inv[16];
    float lsum = 0.0f;
#pragma unroll
    for (int d = 0; d < 16; ++d) {
        mu[d]  = mu_q[b * 16 + d];
        inv[d] = s_inv[d];
        lsum  += s_ls[d];
    }
    const float cb = -lsum - 8.0f * LOG2PI;   // per-b constant part of score

    float best = -INFINITY;
    int   bidx = 0x7fffffff;

    for (int s = tid; s < 4096; s += 256) {
        const float4* row = reinterpret_cast<const float4*>(prior + (size_t)s * 16);
        float acc = 0.0f;
#pragma unroll
        for (int i = 0; i < 4; ++i) {
            float4 v = row[i];
            float z0 = (v.x - mu[4 * i + 0]) * inv[4 * i + 0];
            float z1 = (v.y - mu[4 * i + 1]) * inv[4 * i + 1];
            float z2 = (v.z - mu[4 * i + 2]) * inv[4 * i + 2];
            float z3 = (v.w - mu[4 * i + 3]) * inv[4 * i + 3];
            acc += -0.5f * z0 * z0 - 0.5f * z1 * z1
                 - 0.5f * z2 * z2 - 0.5f * z3 * z3;
        }
        float score = acc + cb - S[s];
        // s increases monotonically per thread -> strict '>' keeps first max
        if (score > best) { best = score; bidx = s; }
    }

    // ---- wave (64-lane) reduction, tie-break: smaller index wins ----
#pragma unroll
    for (int off = 32; off > 0; off >>= 1) {
        float ob = __shfl_down(best, off, 64);
        int   oi = __shfl_down(bidx, off, 64);
        if (ob > best || (ob == best && oi < bidx)) { best = ob; bidx = oi; }
    }

    // ---- cross-wave reduction (4 waves) via LDS ----
    __shared__ float w_best[4];
    __shared__ int   w_idx[4];
    const int wave = tid >> 6;
    if ((tid & 63) == 0) { w_best[wave] = best; w_idx[wave] = bidx; }
    __syncthreads();

    if (tid == 0) {
#pragma unroll
        for (int w = 1; w < 4; ++w) {
            float ob = w_best[w]; int oi = w_idx[w];
            if (ob > best || (ob == best && oi < bidx)) { best = ob; bidx = oi; }
        }
        out_idx[b] = (float)bidx;                    // indices stored as f32
        const float4* row = reinterpret_cast<const float4*>(prior + (size_t)bidx * 16);
        float4* o = reinterpret_cast<float4*>(out_samples + (size_t)b * 16);
#pragma unroll
        for (int i = 0; i < 4; ++i) o[i] = row[i];
    }
}

extern "C" void kernel_launch(void* const* d_in, const int* in_sizes, int n_in,
                              void* d_out, int out_size, void* d_ws, size_t ws_size,
                              hipStream_t stream)
{
    const float* mu_q  = (const float*)d_in[0];   // [1024,16]
    const float* std_q = (const float*)d_in[1];   // [1024,16]
    const float* prior = (const float*)d_in[2];   // [4096,16]
    const float* nlp   = (const float*)d_in[3];   // [4096,16]

    const int bs        = in_sizes[0] / 16;       // 1024
    const int n_samples = in_sizes[2] / 16;       // 4096

    float* out_samples = (float*)d_out;                       // [bs,16]
    float* out_idx     = (float*)d_out + (size_t)bs * 16;     // [bs]
    float* S           = (float*)d_ws;                        // [n_samples]

    nlp_rowsum_kernel<<<(n_samples + 255) / 256, 256, 0, stream>>>(nlp, S, n_samples);
    pfr_argmax_kernel<<<bs, 256, 0, stream>>>(mu_q, std_q, prior, S,
                                              out_samples, out_idx);
}

// Round 2
// 23.208 us; speedup vs baseline: 1.1588x; 1.1588x over previous
//
#include <hip/hip_runtime.h>
#include <math.h>

constexpr int DIM  = 16;
constexpr int NB   = 16;    // batch rows per score-block
constexpr int TILE = 256;   // sample rows per score-block

// ---------------------------------------------------------------------------
// prep: A = mu/var, C = -0.5/var  (per batch element), S[s] = rowsum(nlp)
// ---------------------------------------------------------------------------
__global__ __launch_bounds__(256) void prep_kernel(
    const float* __restrict__ mu_q, const float* __restrict__ std_q,
    const float* __restrict__ nlp,
    float* __restrict__ A, float* __restrict__ C, float* __restrict__ S,
    int n_ac, int n_samples)
{
    const int i = blockIdx.x * 256 + threadIdx.x;
    if (i < n_ac) {
        float sd = std_q[i];
        float w  = 1.0f / (sd * sd);
        A[i] = mu_q[i] * w;
        C[i] = -0.5f * w;
    }
    if (i < n_samples) {
        const float4* r = reinterpret_cast<const float4*>(nlp + (size_t)i * DIM);
        float4 a0 = r[0], a1 = r[1], a2 = r[2], a3 = r[3];
        S[i] = ((a0.x + a0.y) + (a0.z + a0.w)) + ((a1.x + a1.y) + (a1.z + a1.w))
             + ((a2.x + a2.y) + (a2.z + a2.w)) + ((a3.x + a3.y) + (a3.z + a3.w));
    }
}

// ---------------------------------------------------------------------------
// score: block (bt, t) scores NB batch rows vs TILE sample rows.
//   score(b,s) = sum_d fma(p, fma(c, p, a)) - S[s]      (per-b const dropped)
// Partial argmax per (b, tile) -> part[b*ntiles + t] = {score, idx}
// ---------------------------------------------------------------------------
__global__ __launch_bounds__(256) void score_kernel(
    const float* __restrict__ A, const float* __restrict__ C,
    const float* __restrict__ prior, const float* __restrict__ S,
    float2* __restrict__ part, int ntiles)
{
    const int bt  = blockIdx.x;
    const int t   = blockIdx.y;
    const int tid = threadIdx.x;
    const int s   = t * TILE + tid;          // this thread's sample row
    const int b0  = bt * NB;

    // load prior row into registers
    const float4* rp = reinterpret_cast<const float4*>(prior + (size_t)s * DIM);
    float4 q0 = rp[0], q1 = rp[1], q2 = rp[2], q3 = rp[3];
    float p[DIM] = { q0.x, q0.y, q0.z, q0.w,  q1.x, q1.y, q1.z, q1.w,
                     q2.x, q2.y, q2.z, q2.w,  q3.x, q3.y, q3.z, q3.w };
    const float negS = -S[s];

    __shared__ float sc[NB][TILE + 1];       // stride 257 -> 2-way (free) banks

#pragma unroll
    for (int nb = 0; nb < NB; ++nb) {
        const float* a = A + (size_t)(b0 + nb) * DIM;   // wave-uniform -> s_load
        const float* c = C + (size_t)(b0 + nb) * DIM;
        float acc = negS;
#pragma unroll
        for (int d = 0; d < DIM; ++d)
            acc = fmaf(p[d], fmaf(c[d], p[d], a[d]), acc);
        sc[nb][tid] = acc;
    }
    __syncthreads();

    // stage 1: 16 workers per nb, each scans 16 consecutive samples
    const int nb = tid & 15;
    const int k  = tid >> 4;
    float best = -INFINITY; int bi = 0;
#pragma unroll
    for (int j = 0; j < 16; ++j) {
        float v = sc[nb][k * 16 + j];        // ascending j: strict '>' = first max
        if (v > best) { best = v; bi = k * 16 + j; }
    }

    __shared__ float s2v[NB][16];
    __shared__ int   s2i[NB][16];
    s2v[nb][k] = best; s2i[nb][k] = bi;
    __syncthreads();

    // stage 2: thread nb finishes its batch row (k ascending = idx ascending)
    if (tid < NB) {
        float bb = -INFINITY; int bbi = 0;
#pragma unroll
        for (int k2 = 0; k2 < 16; ++k2) {
            float v = s2v[tid][k2];
            if (v > bb) { bb = v; bbi = s2i[tid][k2]; }
        }
        part[(size_t)(b0 + tid) * ntiles + t] =
            make_float2(bb, (float)(t * TILE + bbi));
    }
}

// ---------------------------------------------------------------------------
// reduce: per batch row, argmax over ntiles partials; gather prior row.
// ---------------------------------------------------------------------------
__global__ __launch_bounds__(256) void reduce_kernel(
    const float2* __restrict__ part, const float* __restrict__ prior,
    float* __restrict__ out_samples, float* __restrict__ out_idx,
    int ntiles, int bs)
{
    const int b = blockIdx.x * 256 + threadIdx.x;
    if (b >= bs) return;
    const float2* pb = part + (size_t)b * ntiles;
    float best = -INFINITY; int bidx = 0;
    for (int t = 0; t < ntiles; ++t) {       // ascending t: first max wins ties
        float2 pr = pb[t];
        if (pr.x > best) { best = pr.x; bidx = (int)pr.y; }
    }
    out_idx[b] = (float)bidx;
    const float4* r = reinterpret_cast<const float4*>(prior + (size_t)bidx * DIM);
    float4* o = reinterpret_cast<float4*>(out_samples + (size_t)b * DIM);
    o[0] = r[0]; o[1] = r[1]; o[2] = r[2]; o[3] = r[3];
}

extern "C" void kernel_launch(void* const* d_in, const int* in_sizes, int n_in,
                              void* d_out, int out_size, void* d_ws, size_t ws_size,
                              hipStream_t stream)
{
    const float* mu_q  = (const float*)d_in[0];   // [bs,16]
    const float* std_q = (const float*)d_in[1];   // [bs,16]
    const float* prior = (const float*)d_in[2];   // [n,16]
    const float* nlp   = (const float*)d_in[3];   // [n,16]

    const int bs        = in_sizes[0] / DIM;      // 1024
    const int n_samples = in_sizes[2] / DIM;      // 4096
    const int n_ac      = bs * DIM;
    const int ntiles    = n_samples / TILE;       // 16

    float* out_samples = (float*)d_out;                       // [bs,16]
    float* out_idx     = (float*)d_out + (size_t)bs * DIM;    // [bs]

    float*  A    = (float*)d_ws;                              // [bs*16]
    float*  C    = A + n_ac;                                  // [bs*16]
    float*  S    = C + n_ac;                                  // [n]
    float2* part = (float2*)(S + n_samples);                  // [bs*ntiles]

    prep_kernel<<<(n_ac + 255) / 256, 256, 0, stream>>>(
        mu_q, std_q, nlp, A, C, S, n_ac, n_samples);

    dim3 grid(bs / NB, ntiles);
    score_kernel<<<grid, 256, 0, stream>>>(A, C, prior, S, part, ntiles);

    reduce_kernel<<<(bs + 255) / 256, 256, 0, stream>>>(
        part, prior, out_samples, out_idx, ntiles, bs);
}

// Round 3
// 16.913 us; speedup vs baseline: 1.5901x; 1.3722x over previous
//
#include <hip/hip_runtime.h>
#include <math.h>

constexpr int DIM = 16;
constexpr int NB  = 2;     // batch rows per block
constexpr int BT  = 256;   // threads per block

// ---------------------------------------------------------------------------
// Single fused kernel.
//   score(b,s) = sum_d ( c'[b,d]*p^2 + a[b,d]*p ),  p = prior[s,d]
//   with a = mu/sigma^2, c' = 0.5*(1 - 1/sigma^2)
// (equals the reference's perturbed[b,s] up to a per-b additive constant --
//  argmax-invariant; normal_log_prob is algebraically absorbed.)
// Each block owns NB batch rows and scans ALL n_samples prior rows.
// ---------------------------------------------------------------------------
__global__ __launch_bounds__(BT) void pfr_fused_kernel(
    const float* __restrict__ mu_q, const float* __restrict__ std_q,
    const float* __restrict__ prior,
    float* __restrict__ out_samples, float* __restrict__ out_idx,
    int n_samples, int bs)
{
    const int b0  = blockIdx.x * NB;
    const int tid = threadIdx.x;

    // Per-thread copy of this block's coefficients (block-uniform values).
    float a[NB * DIM], c[NB * DIM];
#pragma unroll
    for (int r = 0; r < NB; ++r) {
        const int bb = min(b0 + r, bs - 1);          // guard (bs % NB == 0 normally)
#pragma unroll
        for (int d = 0; d < DIM; ++d) {
            float sd = std_q[bb * DIM + d];
            float w  = 1.0f / (sd * sd);
            a[r * DIM + d] = mu_q[bb * DIM + d] * w;
            c[r * DIM + d] = 0.5f - 0.5f * w;
        }
    }

    float best[NB]; int bidx[NB];
#pragma unroll
    for (int r = 0; r < NB; ++r) { best[r] = -INFINITY; bidx[r] = 0x7fffffff; }

    for (int s = tid; s < n_samples; s += BT) {
        const float4* rp = reinterpret_cast<const float4*>(prior + (size_t)s * DIM);
        float4 q0 = rp[0], q1 = rp[1], q2 = rp[2], q3 = rp[3];
        float p[DIM] = { q0.x, q0.y, q0.z, q0.w,  q1.x, q1.y, q1.z, q1.w,
                         q2.x, q2.y, q2.z, q2.w,  q3.x, q3.y, q3.z, q3.w };
#pragma unroll
        for (int r = 0; r < NB; ++r) {
            float accA = 0.0f, accB = 0.0f;          // two chains for ILP
#pragma unroll
            for (int d = 0; d < 8; ++d) {
                accA = fmaf(p[d],     fmaf(c[r*DIM+d],   p[d],   a[r*DIM+d]),   accA);
                accB = fmaf(p[d+8],   fmaf(c[r*DIM+d+8], p[d+8], a[r*DIM+d+8]), accB);
            }
            float sc = accA + accB;
            // s ascends per thread -> strict '>' keeps the first (smallest) idx
            if (sc > best[r]) { best[r] = sc; bidx[r] = s; }
        }
    }

    // ---- wave (64-lane) butterfly reduction, tie-break: smaller idx ----
#pragma unroll
    for (int off = 32; off >= 1; off >>= 1) {
#pragma unroll
        for (int r = 0; r < NB; ++r) {
            float ob = __shfl_xor(best[r], off, 64);
            int   oi = __shfl_xor(bidx[r], off, 64);
            if (ob > best[r] || (ob == best[r] && oi < bidx[r])) {
                best[r] = ob; bidx[r] = oi;
            }
        }
    }

    // ---- cross-wave (4 waves) via tiny LDS ----
    __shared__ float wv[4][NB];
    __shared__ int   wi[4][NB];
    const int wave = tid >> 6;
    if ((tid & 63) == 0) {
#pragma unroll
        for (int r = 0; r < NB; ++r) { wv[wave][r] = best[r]; wi[wave][r] = bidx[r]; }
    }
    __syncthreads();

    if (tid < NB && (b0 + tid) < bs) {
        float bb = wv[0][tid]; int bbi = wi[0][tid];
#pragma unroll
        for (int w = 1; w < 4; ++w) {
            float ob = wv[w][tid]; int oi = wi[w][tid];
            if (ob > bb || (ob == bb && oi < bbi)) { bb = ob; bbi = oi; }
        }
        out_idx[b0 + tid] = (float)bbi;
        const float4* r4 = reinterpret_cast<const float4*>(prior + (size_t)bbi * DIM);
        float4* o = reinterpret_cast<float4*>(out_samples + (size_t)(b0 + tid) * DIM);
        o[0] = r4[0]; o[1] = r4[1]; o[2] = r4[2]; o[3] = r4[3];
    }
}

extern "C" void kernel_launch(void* const* d_in, const int* in_sizes, int n_in,
                              void* d_out, int out_size, void* d_ws, size_t ws_size,
                              hipStream_t stream)
{
    const float* mu_q  = (const float*)d_in[0];   // [bs,16]
    const float* std_q = (const float*)d_in[1];   // [bs,16]
    const float* prior = (const float*)d_in[2];   // [n,16]
    // d_in[3] (normal_log_prob) is algebraically absorbed -- unused.

    const int bs        = in_sizes[0] / DIM;      // 1024
    const int n_samples = in_sizes[2] / DIM;      // 4096

    float* out_samples = (float*)d_out;                       // [bs,16]
    float* out_idx     = (float*)d_out + (size_t)bs * DIM;    // [bs]

    const int nblocks = (bs + NB - 1) / NB;       // 512
    pfr_fused_kernel<<<nblocks, BT, 0, stream>>>(
        mu_q, std_q, prior, out_samples, out_idx, n_samples, bs);
}